// Round 6
// baseline (253.038 us; speedup 1.0000x reference)
//
#include <hip/hip_runtime.h>
#include <cstdint>
#include <cstddef>

typedef unsigned short u16;
typedef unsigned int u32;
typedef __attribute__((ext_vector_type(8))) short short8;
typedef __attribute__((ext_vector_type(4))) float f32x4;

#define T_SEQ 2048
#define BT_ROWS 16384

// ---------- helpers ----------
__device__ __forceinline__ u16 f2bf(float x) {
  union { float f; u32 u; } v; v.f = x;
  u32 r = v.u + 0x7fffu + ((v.u >> 16) & 1u);
  return (u16)(r >> 16);
}
// pack two floats -> two bf16 in one u32 (lo in low half)
__device__ __forceinline__ u32 pkbf(float lo, float hi) {
  union { float f; u32 u; } a, b; a.f = lo; b.f = hi;
  const u32 ra = a.u + 0x7fffu + ((a.u >> 16) & 1u);
  const u32 rb = b.u + 0x7fffu + ((b.u >> 16) & 1u);
  return __builtin_amdgcn_perm(rb, ra, 0x07060302);
}
__device__ __forceinline__ float wave_bcast_sum(float x) {
#pragma unroll
  for (int off = 32; off > 0; off >>= 1) x += __shfl_down(x, off);
  return __shfl(x, 0);
}
__device__ __forceinline__ void gl_lds16(const void* g, void* l) {
  __builtin_amdgcn_global_load_lds((const __attribute__((address_space(1))) u32*)g,
                                   (__attribute__((address_space(3))) u32*)l, 16, 0, 0);
}
// tanh-form GELU; |diff| vs erf ~3e-4
__device__ __forceinline__ float gelu_f(float x) {
  float z = 1.5957691216057308f * x * (1.0f + 0.044715f * x * x);
  float e = __expf(z);
  return x - x * __builtin_amdgcn_rcpf(1.0f + e);
}
// release-barrier: publish LDS writes, do NOT drain vmcnt (keep global loads flying)
__device__ __forceinline__ void lgkm_barrier() {
  asm volatile("s_waitcnt lgkmcnt(0)" ::: "memory");
  __builtin_amdgcn_s_barrier();
}

// ---------- transpose+convert all 3 weights + zero logits ----------
__global__ __launch_bounds__(256) void tcvt_all(const float* __restrict__ Wv,
                                                const float* __restrict__ Wa,
                                                const float* __restrict__ W1,
                                                u16* __restrict__ wvT,
                                                u16* __restrict__ waT,
                                                u16* __restrict__ w1T,
                                                float* __restrict__ logits) {
  int b = blockIdx.x;
  if (b >= 1216) {  // 64 blocks zero the 16384-float logits buffer
    logits[(b - 1216) * 256 + threadIdx.x] = 0.0f;
    return;
  }
  __shared__ float tile[32][33];
  const float* in; u16* out; int K, N, bx, by;
  if (b < 256)      { in = Wv; out = wvT; K = 1024; N = 256;  bx = b & 31;  by = b >> 5; }
  else if (b < 448) { b -= 256; in = Wa; out = waT; K = 768; N = 256;  bx = b % 24; by = b / 24; }
  else              { b -= 448; in = W1; out = w1T; K = 768; N = 1024; bx = b % 24; by = b / 24; }
  const int k0 = bx * 32, n0 = by * 32;
  const int tx = threadIdx.x & 31, ty = threadIdx.x >> 5;
#pragma unroll
  for (int r = 0; r < 4; r++)
    tile[ty + r * 8][tx] = in[(size_t)(k0 + ty + r * 8) * N + n0 + tx];
  __syncthreads();
#pragma unroll
  for (int r = 0; r < 4; r++)
    out[(size_t)(n0 + ty + r * 8) * K + k0 + tx] = f2bf(tile[tx][ty + r * 8]);
}

// ---------- projection GEMM with FUSED LayerNorm, tile 64x256 (r3 config) ----------
// Reverted to the round-3 shape: Mt=64, 256 thr, grid 512 (2 blocks/CU).
// Empirical law (r0-r5): dur = vmem_bytes / ~6.5 TB/s, valid only at >=2
// blocks/CU (1/CU collapses to ~4 TB/s — r5). All grid-512 tilings of this
// problem move the same 370 MB, so this config sits at the per-CU vmem cap.
// Keeps: K-phase rotation (channel de-camping, r3 +13%), B direct->registers
// (weights L2-resident), lgkm-only barrier (loads fly across it).
template <int K>
__device__ __forceinline__ void proj_body(const float* __restrict__ A,
                                          const u16* __restrict__ Bt,
                                          const float* __restrict__ bias,
                                          float* __restrict__ C,
                                          int m0, u16* As, int k0) {
  constexpr int NT = K / 64;
  const int tid = threadIdx.x;
  const int wave = tid >> 6, lane = tid & 63, qm = lane & 15, quad = lane >> 4;
  const int cw = wave * 64;   // wave owns a 64-col quarter, all 64 rows

  // A register staging: thread owns row ar = tid>>2, 16 consecutive floats.
  const int ar = tid >> 2;
  const float* Arow = A + (size_t)(m0 + ar) * K + (tid & 3) * 4;
  int awAddr[4];
#pragma unroll
  for (int g = 0; g < 4; g++) {
    const int cg = ((tid & 3) >> 1) + 2 * g;
    awAddr[g] = ar * 64 + ((cg ^ (ar & 7)) * 8) + (tid & 1) * 4;
  }
  // B fragment row pointers (row = output col); chunk offset = quad*8 + s*32
  const u16* brow[4];
#pragma unroll
  for (int j = 0; j < 4; j++)
    brow[j] = Bt + (size_t)(cw + j * 16 + qm) * K + quad * 8;

  f32x4 acc[4][4] = {};
  short8 bfrag[2][8];
  float4 p[4];

  int koff = k0;   // current K-tile element offset (circular)

  // ---- prologue: A(koff) -> As[0], B(koff) -> bfrag[0] ----
#pragma unroll
  for (int g = 0; g < 4; g++) p[g] = *(const float4*)(Arow + koff + g * 16);
#pragma unroll
  for (int s = 0; s < 2; s++)
#pragma unroll
    for (int j = 0; j < 4; j++)
      bfrag[0][s * 4 + j] = *(const short8*)(brow[j] + koff + s * 32);
#pragma unroll
  for (int g = 0; g < 4; g++) {
    uint2 w; w.x = pkbf(p[g].x, p[g].y); w.y = pkbf(p[g].z, p[g].w);
    *(uint2*)&As[awAddr[g]] = w;
  }
  lgkm_barrier();

#pragma unroll
  for (int t = 0; t < NT; t++) {
    const int cb = t & 1, nb = cb ^ 1;
    int knext = koff + 64;
    if (knext == K) knext = 0;   // circular K walk
    if (t + 1 < NT) {  // issue next-tile loads; they fly across the barrier
#pragma unroll
      for (int g = 0; g < 4; g++)
        p[g] = *(const float4*)(Arow + knext + g * 16);
#pragma unroll
      for (int s = 0; s < 2; s++)
#pragma unroll
        for (int j = 0; j < 4; j++)
          bfrag[nb][s * 4 + j] = *(const short8*)(brow[j] + knext + s * 32);
    }
#pragma unroll
    for (int s = 0; s < 2; s++) {
      short8 af[4];
#pragma unroll
      for (int i = 0; i < 4; i++) {
        const int r = i * 16 + qm;
        af[i] = *(const short8*)&As[cb * 4096 + r * 64 + ((s * 4 + quad) ^ (r & 7)) * 8];
      }
      __builtin_amdgcn_s_setprio(1);
#pragma unroll
      for (int i = 0; i < 4; i++)
#pragma unroll
        for (int j = 0; j < 4; j++)
          acc[i][j] = __builtin_amdgcn_mfma_f32_16x16x32_bf16(
              af[i], bfrag[cb][s * 4 + j], acc[i][j], 0, 0, 0);
      __builtin_amdgcn_s_setprio(0);
    }
    if (t + 1 < NT) {  // convert+publish next A tile (p landed under MFMAs)
#pragma unroll
      for (int g = 0; g < 4; g++) {
        uint2 w; w.x = pkbf(p[g].x, p[g].y); w.y = pkbf(p[g].z, p[g].w);
        *(uint2*)&As[nb * 4096 + awAddr[g]] = w;
      }
      lgkm_barrier();
    }
    koff = knext;
  }

  // ---- fused bias + LayerNorm epilogue over 64 rows ----
  float bcol[4];
#pragma unroll
  for (int j = 0; j < 4; j++) bcol[j] = bias[cw + j * 16 + qm];
#pragma unroll
  for (int i = 0; i < 4; i++)
#pragma unroll
    for (int j = 0; j < 4; j++)
#pragma unroll
      for (int r = 0; r < 4; r++)
        acc[i][j][r] += bcol[j];
  float s1[4][4], s2[4][4];
#pragma unroll
  for (int i = 0; i < 4; i++)
#pragma unroll
    for (int r = 0; r < 4; r++) {
      float a1 = 0, a2 = 0;
#pragma unroll
      for (int j = 0; j < 4; j++) { a1 += acc[i][j][r]; a2 += acc[i][j][r] * acc[i][j][r]; }
#pragma unroll
      for (int off = 1; off < 16; off <<= 1) {
        a1 += __shfl_xor(a1, off);
        a2 += __shfl_xor(a2, off);
      }
      s1[i][r] = a1; s2[i][r] = a2;
    }
  __syncthreads();          // all waves done with K-loop LDS before scratch reuse
  float* red = (float*)As;
  if (qm == 0) {
#pragma unroll
    for (int i = 0; i < 4; i++)
#pragma unroll
      for (int r = 0; r < 4; r++) {
        const int row = i * 16 + quad * 4 + r;
        red[row * 8 + wave * 2] = s1[i][r];
        red[row * 8 + wave * 2 + 1] = s2[i][r];
      }
  }
  __syncthreads();
#pragma unroll
  for (int i = 0; i < 4; i++)
#pragma unroll
    for (int r = 0; r < 4; r++) {
      const int row = i * 16 + quad * 4 + r;   // D: row = quad*4 + reg (+ i*16)
      const float4 q1 = *(const float4*)&red[row * 8];
      const float4 q2 = *(const float4*)&red[row * 8 + 4];
      const float st = q1.x + q1.z + q2.x + q2.z;
      const float st2 = q1.y + q1.w + q2.y + q2.w;
      const float mu = st * (1.0f / 256.0f);
      const float var = st2 * (1.0f / 256.0f) - mu * mu;
      const float inv = rsqrtf(var + 1e-5f);
#pragma unroll
      for (int j = 0; j < 4; j++)
        C[(size_t)(m0 + row) * 256 + cw + j * 16 + qm] = (acc[i][j][r] - mu) * inv;
    }
}

__global__ __launch_bounds__(256, 2) void proj_ln(const float* __restrict__ Vin,
                                                  const float* __restrict__ Ain,
                                                  const u16* __restrict__ wvT,
                                                  const u16* __restrict__ waT,
                                                  const float* __restrict__ bv,
                                                  const float* __restrict__ ba,
                                                  float* __restrict__ vOut,
                                                  float* __restrict__ aOut) {
  __shared__ __align__(16) u16 As[2][64 * 64];   // 16 KB total (A dbuf, bf16)
  int b = blockIdx.x;
  if (b < 256)
    proj_body<1024>(Vin, wvT, bv, vOut, b * 64, &As[0][0], (b & 15) * 64);
  else {
    b -= 256;
    proj_body<768>(Ain, waT, ba, aOut, b * 64, &As[0][0], (b % 12) * 64);
  }
}

// ---------- MLP GEMM: tile 256x128, 512 thr, grid (8,64)=512 = 2 blocks/CU ----------
// v3: BYTES + CONCURRENCY. r0 (128x128, grid 1024) moved 403 MB; r5 (256x256,
// grid 256 = 1/CU) hit the concurrency collapse. 256x128 @ grid 512 keeps
// 2 blocks/CU and moves 302 MB (w1T re-read 201->100 MB, xb re-read 8x kept).
// __launch_bounds__(512,4): k = w*4/(512/64) = 2 blocks/CU, VGPR cap 128.
__global__ __launch_bounds__(512, 4) void gemm_gelu_w2(const u16* __restrict__ Axb,
                                                       const u16* __restrict__ Bt,
                                                       const float* __restrict__ b1,
                                                       const float* __restrict__ W2,
                                                       float* __restrict__ logits) {
  constexpr int K = 768;
  __shared__ u16 As[256 * 64];   // 32 KB
  __shared__ u16 Bs[128 * 64];   // 16 KB
  const int tid = threadIdx.x;       // 0..511
  const int n0 = blockIdx.x * 128;   // x = n: consecutive blocks share A m-tile
  const int m0 = blockIdx.y * 256;
  const int wave = tid >> 6, lane = tid & 63, qm = lane & 15, quad = lane >> 4;
  const int rw = (wave >> 1) * 64, cw = (wave & 1) * 64;  // 4 row-grps x 2 col-grps

  // staging: instr g covers rows (tid>>3)+g*64; in-row chunk (tid&7), source
  // pre-swizzled by xor-8 so the swizzled read below finds chunk c at c^(r&7).
  const u16* Ap[4];
#pragma unroll
  for (int g = 0; g < 4; g++) {
    const int r = (tid >> 3) + g * 64;
    const int cc = (tid & 7) ^ (r & 7);
    Ap[g] = Axb + (size_t)(m0 + r) * K + cc * 8;
  }
  const u16* Bp[2];
#pragma unroll
  for (int g = 0; g < 2; g++) {
    const int r = (tid >> 3) + g * 64;
    const int cc = (tid & 7) ^ (r & 7);
    Bp[g] = Bt + (size_t)(n0 + r) * K + cc * 8;
  }

  f32x4 acc[4][4] = {};
  for (int kt = 0; kt < K; kt += 64) {
#pragma unroll
    for (int g = 0; g < 4; g++) gl_lds16(Ap[g] + kt, &As[(tid + g * 512) * 8]);
#pragma unroll
    for (int g = 0; g < 2; g++) gl_lds16(Bp[g] + kt, &Bs[(tid + g * 512) * 8]);
    __syncthreads();
#pragma unroll
    for (int s = 0; s < 2; s++) {
      short8 af[4], bfr[4];
#pragma unroll
      for (int i = 0; i < 4; i++) {
        const int r = rw + i * 16 + qm;                       // 0..255
        af[i] = *(const short8*)&As[r * 64 + ((s * 4 + quad) ^ (r & 7)) * 8];
      }
#pragma unroll
      for (int j = 0; j < 4; j++) {
        const int r = cw + j * 16 + qm;                       // 0..127
        bfr[j] = *(const short8*)&Bs[r * 64 + ((s * 4 + quad) ^ (r & 7)) * 8];
      }
#pragma unroll
      for (int i = 0; i < 4; i++)
#pragma unroll
        for (int j = 0; j < 4; j++)
          acc[i][j] = __builtin_amdgcn_mfma_f32_16x16x32_bf16(af[i], bfr[j], acc[i][j], 0, 0, 0);
    }
    __syncthreads();
  }

  // epilogue: partial logit = sum_j gelu(acc+b1)*W2; reduce over qm lanes; 1 atomic/row
  float w2j[4], bc[4];
#pragma unroll
  for (int j = 0; j < 4; j++) {
    const int col = n0 + cw + j * 16 + qm;
    w2j[j] = W2[col];
    bc[j] = b1[col];
  }
#pragma unroll
  for (int i = 0; i < 4; i++) {
#pragma unroll
    for (int r = 0; r < 4; r++) {
      float p = 0.0f;
#pragma unroll
      for (int j = 0; j < 4; j++)
        p += gelu_f(acc[i][j][r] + bc[j]) * w2j[j];
      p += __shfl_xor(p, 1);
      p += __shfl_xor(p, 2);
      p += __shfl_xor(p, 4);
      p += __shfl_xor(p, 8);
      if (qm == 0)
        atomicAdd(&logits[m0 + rw + i * 16 + quad * 4 + r], p);
    }
  }
}

// ---------- fused: fractional shift + window avg + l2norm(actx,v) + concat ----------
__global__ __launch_bounds__(256) void shift_norm(const float* __restrict__ a,
                                                  const float* __restrict__ v,
                                                  float* __restrict__ actx,
                                                  u16* __restrict__ xb,
                                                  const float* __restrict__ theta) {
  const int row = blockIdx.x * 4 + (threadIdx.x >> 6);
  const int lane = threadIdx.x & 63;
  const int d4 = lane * 4;
  const int bb = row >> 11;
  const int t = row & (T_SEQ - 1);
  const float th = fminf(fmaxf(theta[0], -12.0f), 12.0f);
  const float delta = 2.0f + 4.0f * (1.0f / (1.0f + expf(-th)));
  const float dl = fminf(fmaxf(delta, 0.0f), (float)(T_SEQ - 1));
  const float nf = floorf(dl);
  const float alpha = dl - nf;
  const int ni = (int)nf;
  const float center = fminf(fmaxf((float)t + delta, 0.0f), (float)t);
  float sx = 0, sy = 0, sz = 0, sw = 0, cnt = 0.0f;
  const float* ab = a + (size_t)bb * T_SEQ * 256;
#pragma unroll
  for (int j = 0; j < 6; j++) {
    const int tau = t - 5 + j;
    if (tau < 0) continue;
    if (fabsf((float)tau - center) > 5.0f) continue;
    cnt += 1.0f;
    const int i0 = min(max(tau - ni, 0), T_SEQ - 1);
    const int i1 = min(i0 + 1, T_SEQ - 1);
    const float4 a0 = *(const float4*)&ab[(size_t)i0 * 256 + d4];
    const float4 a1 = *(const float4*)&ab[(size_t)i1 * 256 + d4];
    sx += a0.x + alpha * (a1.x - a0.x);
    sy += a0.y + alpha * (a1.y - a0.y);
    sz += a0.z + alpha * (a1.z - a0.z);
    sw += a0.w + alpha * (a1.w - a0.w);
  }
  const float sc = 1.0f / fmaxf(cnt, 1e-8f);
  float4 o; o.x = sx * sc; o.y = sy * sc; o.z = sz * sc; o.w = sw * sc;
  *(float4*)&actx[(size_t)row * 256 + d4] = o;
  const float4 vv = *(const float4*)&v[(size_t)row * 256 + d4];
  float sa2 = o.x * o.x + o.y * o.y + o.z * o.z + o.w * o.w;
  float sv2 = vv.x * vv.x + vv.y * vv.y + vv.z * vv.z + vv.w * vv.w;
  sa2 = wave_bcast_sum(sa2);
  sv2 = wave_bcast_sum(sv2);
  const float ia = 1.0f / fmaxf(sqrtf(sa2), 1e-8f);
  const float iv = 1.0f / fmaxf(sqrtf(sv2), 1e-8f);
  const float anx = o.x * ia, any_ = o.y * ia, anz = o.z * ia, anw = o.w * ia;
  const float vnx = vv.x * iv, vny = vv.y * iv, vnz = vv.z * iv, vnw = vv.w * iv;
  u16* xr = xb + (size_t)row * 768;
  u32 pa[2] = {pkbf(anx, any_), pkbf(anz, anw)};
  u32 pv[2] = {pkbf(vnx, vny), pkbf(vnz, vnw)};
  u32 pp[2] = {pkbf(anx * vnx, any_ * vny), pkbf(anz * vnz, anw * vnw)};
  *(uint2*)&xr[d4] = *(uint2*)pa;
  *(uint2*)&xr[256 + d4] = *(uint2*)pv;
  *(uint2*)&xr[512 + d4] = *(uint2*)pp;
}

// ---------- gate + mix ----------
__global__ __launch_bounds__(256) void gate_mix(const float* __restrict__ logits,
                                                const float* __restrict__ b2,
                                                const float* __restrict__ actx,
                                                const float* __restrict__ v,
                                                float* __restrict__ out) {
  const int row = blockIdx.x * 4 + (threadIdx.x >> 6);
  const int lane = threadIdx.x & 63;
  const float l = fminf(fmaxf(logits[row] + b2[0], -12.0f), 12.0f);
  float g = 1.0f / (1.0f + expf(-l));
  g = fminf(fmaxf(g, 0.05f), 0.95f);
  const float4 aa = *(const float4*)&actx[(size_t)row * 256 + lane * 4];
  const float4 vv = *(const float4*)&v[(size_t)row * 256 + lane * 4];
  float4 o;
  o.x = g * aa.x + (1.0f - g) * vv.x;
  o.y = g * aa.y + (1.0f - g) * vv.y;
  o.z = g * aa.z + (1.0f - g) * vv.z;
  o.w = g * aa.w + (1.0f - g) * vv.w;
  *(float4*)&out[(size_t)row * 256 + lane * 4] = o;
}

// ---------- launch ----------
extern "C" void kernel_launch(void* const* d_in, const int* in_sizes, int n_in,
                              void* d_out, int out_size, void* d_ws, size_t ws_size,
                              hipStream_t stream) {
  const float* video = (const float*)d_in[0];
  const float* audio = (const float*)d_in[1];
  const float* Wv    = (const float*)d_in[2];
  const float* bv    = (const float*)d_in[3];
  const float* Wa    = (const float*)d_in[4];
  const float* ba    = (const float*)d_in[5];
  const float* theta = (const float*)d_in[6];
  const float* W1    = (const float*)d_in[7];
  const float* b1    = (const float*)d_in[8];
  const float* W2    = (const float*)d_in[9];
  const float* b2    = (const float*)d_in[10];
  float* out = (float*)d_out;
  char* ws = (char*)d_ws;

  const size_t OFF_WVT = 0;          // [256][1024] bf16 = 512 KB
  const size_t OFF_WAT = 524288;     // [256][768]  bf16 = 384 KB
  const size_t OFF_W1T = 917504;     // [1024][768] bf16 = 1.5 MB
  const size_t OFF_LOG = 2490368;    // [16384] f32 = 64 KB
  const size_t OFF_V   = 2555904;    // [16384][256] f32 = 16 MB (LN'd v)
  const size_t OFF_A   = 19333120;   // [16384][256] f32 = 16 MB (LN'd a)
  const size_t OFF_ACTX= 36110336;   // [16384][256] f32 = 16 MB
  const size_t OFF_XB  = 52887552;   // [16384][768] bf16 = 24 MB

  u16* wvT = (u16*)(ws + OFF_WVT);
  u16* waT = (u16*)(ws + OFF_WAT);
  u16* w1T = (u16*)(ws + OFF_W1T);
  float* logits = (float*)(ws + OFF_LOG);
  float* v    = (float*)(ws + OFF_V);
  float* a    = (float*)(ws + OFF_A);
  float* actx = (float*)(ws + OFF_ACTX);
  u16* xb = (u16*)(ws + OFF_XB);

  tcvt_all<<<1280, 256, 0, stream>>>(Wv, Wa, W1, wvT, waT, w1T, logits);
  proj_ln<<<512, 256, 0, stream>>>(video, audio, wvT, waT, bv, ba, v, a);
  shift_norm<<<BT_ROWS / 4, 256, 0, stream>>>(a, v, actx, xb, theta);
  gemm_gelu_w2<<<dim3(8, 64), 512, 0, stream>>>(xb, w1T, b1, W2, logits);
  gate_mix<<<BT_ROWS / 4, 256, 0, stream>>>(logits, b2, actx, v, out);
}

// Round 7
// 249.155 us; speedup vs baseline: 1.0156x; 1.0156x over previous
//
#include <hip/hip_runtime.h>
#include <cstdint>
#include <cstddef>

typedef unsigned short u16;
typedef unsigned int u32;
typedef __attribute__((ext_vector_type(8))) short short8;
typedef __attribute__((ext_vector_type(4))) float f32x4;

#define T_SEQ 2048
#define BT_ROWS 16384

// ---------- helpers ----------
__device__ __forceinline__ u16 f2bf(float x) {
  union { float f; u32 u; } v; v.f = x;
  u32 r = v.u + 0x7fffu + ((v.u >> 16) & 1u);
  return (u16)(r >> 16);
}
// pack two floats -> two bf16 in one u32 (lo in low half)
__device__ __forceinline__ u32 pkbf(float lo, float hi) {
  union { float f; u32 u; } a, b; a.f = lo; b.f = hi;
  const u32 ra = a.u + 0x7fffu + ((a.u >> 16) & 1u);
  const u32 rb = b.u + 0x7fffu + ((b.u >> 16) & 1u);
  return __builtin_amdgcn_perm(rb, ra, 0x07060302);
}
__device__ __forceinline__ float wave_bcast_sum(float x) {
#pragma unroll
  for (int off = 32; off > 0; off >>= 1) x += __shfl_down(x, off);
  return __shfl(x, 0);
}
__device__ __forceinline__ void gl_lds16(const void* g, void* l) {
  __builtin_amdgcn_global_load_lds((const __attribute__((address_space(1))) u32*)g,
                                   (__attribute__((address_space(3))) u32*)l, 16, 0, 0);
}
// tanh-form GELU; |diff| vs erf ~3e-4
__device__ __forceinline__ float gelu_f(float x) {
  float z = 1.5957691216057308f * x * (1.0f + 0.044715f * x * x);
  float e = __expf(z);
  return x - x * __builtin_amdgcn_rcpf(1.0f + e);
}
// release-barrier: publish LDS writes, do NOT drain vmcnt (keep global loads flying)
__device__ __forceinline__ void lgkm_barrier() {
  asm volatile("s_waitcnt lgkmcnt(0)" ::: "memory");
  __builtin_amdgcn_s_barrier();
}

// ---------- transpose+convert all 3 weights + zero logits ----------
__global__ __launch_bounds__(256) void tcvt_all(const float* __restrict__ Wv,
                                                const float* __restrict__ Wa,
                                                const float* __restrict__ W1,
                                                u16* __restrict__ wvT,
                                                u16* __restrict__ waT,
                                                u16* __restrict__ w1T,
                                                float* __restrict__ logits) {
  int b = blockIdx.x;
  if (b >= 1216) {  // 64 blocks zero the 16384-float logits buffer
    logits[(b - 1216) * 256 + threadIdx.x] = 0.0f;
    return;
  }
  __shared__ float tile[32][33];
  const float* in; u16* out; int K, N, bx, by;
  if (b < 256)      { in = Wv; out = wvT; K = 1024; N = 256;  bx = b & 31;  by = b >> 5; }
  else if (b < 448) { b -= 256; in = Wa; out = waT; K = 768; N = 256;  bx = b % 24; by = b / 24; }
  else              { b -= 448; in = W1; out = w1T; K = 768; N = 1024; bx = b % 24; by = b / 24; }
  const int k0 = bx * 32, n0 = by * 32;
  const int tx = threadIdx.x & 31, ty = threadIdx.x >> 5;
#pragma unroll
  for (int r = 0; r < 4; r++)
    tile[ty + r * 8][tx] = in[(size_t)(k0 + ty + r * 8) * N + n0 + tx];
  __syncthreads();
#pragma unroll
  for (int r = 0; r < 4; r++)
    out[(size_t)(n0 + ty + r * 8) * K + k0 + tx] = f2bf(tile[tx][ty + r * 8]);
}

// ---------- projection GEMM with FUSED LayerNorm, tile 64x256 (r3 config) ----------
// Mt=64, 256 thr, grid 512 (2 blocks/CU) — empirically the best config (58 µs,
// at the per-CU vmem request cap). K-phase rotation + B-in-registers +
// lgkm-only barrier. DO NOT retile: grid-512 tilings are bytes-invariant.
template <int K>
__device__ __forceinline__ void proj_body(const float* __restrict__ A,
                                          const u16* __restrict__ Bt,
                                          const float* __restrict__ bias,
                                          float* __restrict__ C,
                                          int m0, u16* As, int k0) {
  constexpr int NT = K / 64;
  const int tid = threadIdx.x;
  const int wave = tid >> 6, lane = tid & 63, qm = lane & 15, quad = lane >> 4;
  const int cw = wave * 64;   // wave owns a 64-col quarter, all 64 rows

  // A register staging: thread owns row ar = tid>>2, 16 consecutive floats.
  const int ar = tid >> 2;
  const float* Arow = A + (size_t)(m0 + ar) * K + (tid & 3) * 4;
  int awAddr[4];
#pragma unroll
  for (int g = 0; g < 4; g++) {
    const int cg = ((tid & 3) >> 1) + 2 * g;
    awAddr[g] = ar * 64 + ((cg ^ (ar & 7)) * 8) + (tid & 1) * 4;
  }
  // B fragment row pointers (row = output col); chunk offset = quad*8 + s*32
  const u16* brow[4];
#pragma unroll
  for (int j = 0; j < 4; j++)
    brow[j] = Bt + (size_t)(cw + j * 16 + qm) * K + quad * 8;

  f32x4 acc[4][4] = {};
  short8 bfrag[2][8];
  float4 p[4];

  int koff = k0;   // current K-tile element offset (circular)

  // ---- prologue: A(koff) -> As[0], B(koff) -> bfrag[0] ----
#pragma unroll
  for (int g = 0; g < 4; g++) p[g] = *(const float4*)(Arow + koff + g * 16);
#pragma unroll
  for (int s = 0; s < 2; s++)
#pragma unroll
    for (int j = 0; j < 4; j++)
      bfrag[0][s * 4 + j] = *(const short8*)(brow[j] + koff + s * 32);
#pragma unroll
  for (int g = 0; g < 4; g++) {
    uint2 w; w.x = pkbf(p[g].x, p[g].y); w.y = pkbf(p[g].z, p[g].w);
    *(uint2*)&As[awAddr[g]] = w;
  }
  lgkm_barrier();

#pragma unroll
  for (int t = 0; t < NT; t++) {
    const int cb = t & 1, nb = cb ^ 1;
    int knext = koff + 64;
    if (knext == K) knext = 0;   // circular K walk
    if (t + 1 < NT) {  // issue next-tile loads; they fly across the barrier
#pragma unroll
      for (int g = 0; g < 4; g++)
        p[g] = *(const float4*)(Arow + knext + g * 16);
#pragma unroll
      for (int s = 0; s < 2; s++)
#pragma unroll
        for (int j = 0; j < 4; j++)
          bfrag[nb][s * 4 + j] = *(const short8*)(brow[j] + knext + s * 32);
    }
#pragma unroll
    for (int s = 0; s < 2; s++) {
      short8 af[4];
#pragma unroll
      for (int i = 0; i < 4; i++) {
        const int r = i * 16 + qm;
        af[i] = *(const short8*)&As[cb * 4096 + r * 64 + ((s * 4 + quad) ^ (r & 7)) * 8];
      }
      __builtin_amdgcn_s_setprio(1);
#pragma unroll
      for (int i = 0; i < 4; i++)
#pragma unroll
        for (int j = 0; j < 4; j++)
          acc[i][j] = __builtin_amdgcn_mfma_f32_16x16x32_bf16(
              af[i], bfrag[cb][s * 4 + j], acc[i][j], 0, 0, 0);
      __builtin_amdgcn_s_setprio(0);
    }
    if (t + 1 < NT) {  // convert+publish next A tile (p landed under MFMAs)
#pragma unroll
      for (int g = 0; g < 4; g++) {
        uint2 w; w.x = pkbf(p[g].x, p[g].y); w.y = pkbf(p[g].z, p[g].w);
        *(uint2*)&As[nb * 4096 + awAddr[g]] = w;
      }
      lgkm_barrier();
    }
    koff = knext;
  }

  // ---- fused bias + LayerNorm epilogue over 64 rows ----
  float bcol[4];
#pragma unroll
  for (int j = 0; j < 4; j++) bcol[j] = bias[cw + j * 16 + qm];
#pragma unroll
  for (int i = 0; i < 4; i++)
#pragma unroll
    for (int j = 0; j < 4; j++)
#pragma unroll
      for (int r = 0; r < 4; r++)
        acc[i][j][r] += bcol[j];
  float s1[4][4], s2[4][4];
#pragma unroll
  for (int i = 0; i < 4; i++)
#pragma unroll
    for (int r = 0; r < 4; r++) {
      float a1 = 0, a2 = 0;
#pragma unroll
      for (int j = 0; j < 4; j++) { a1 += acc[i][j][r]; a2 += acc[i][j][r] * acc[i][j][r]; }
#pragma unroll
      for (int off = 1; off < 16; off <<= 1) {
        a1 += __shfl_xor(a1, off);
        a2 += __shfl_xor(a2, off);
      }
      s1[i][r] = a1; s2[i][r] = a2;
    }
  __syncthreads();          // all waves done with K-loop LDS before scratch reuse
  float* red = (float*)As;
  if (qm == 0) {
#pragma unroll
    for (int i = 0; i < 4; i++)
#pragma unroll
      for (int r = 0; r < 4; r++) {
        const int row = i * 16 + quad * 4 + r;
        red[row * 8 + wave * 2] = s1[i][r];
        red[row * 8 + wave * 2 + 1] = s2[i][r];
      }
  }
  __syncthreads();
#pragma unroll
  for (int i = 0; i < 4; i++)
#pragma unroll
    for (int r = 0; r < 4; r++) {
      const int row = i * 16 + quad * 4 + r;   // D: row = quad*4 + reg (+ i*16)
      const float4 q1 = *(const float4*)&red[row * 8];
      const float4 q2 = *(const float4*)&red[row * 8 + 4];
      const float st = q1.x + q1.z + q2.x + q2.z;
      const float st2 = q1.y + q1.w + q2.y + q2.w;
      const float mu = st * (1.0f / 256.0f);
      const float var = st2 * (1.0f / 256.0f) - mu * mu;
      const float inv = rsqrtf(var + 1e-5f);
#pragma unroll
      for (int j = 0; j < 4; j++)
        C[(size_t)(m0 + row) * 256 + cw + j * 16 + qm] = (acc[i][j][r] - mu) * inv;
    }
}

__global__ __launch_bounds__(256, 2) void proj_ln(const float* __restrict__ Vin,
                                                  const float* __restrict__ Ain,
                                                  const u16* __restrict__ wvT,
                                                  const u16* __restrict__ waT,
                                                  const float* __restrict__ bv,
                                                  const float* __restrict__ ba,
                                                  float* __restrict__ vOut,
                                                  float* __restrict__ aOut) {
  __shared__ __align__(16) u16 As[2][64 * 64];   // 16 KB total (A dbuf, bf16)
  int b = blockIdx.x;
  if (b < 256)
    proj_body<1024>(Vin, wvT, bv, vOut, b * 64, &As[0][0], (b & 15) * 64);
  else {
    b -= 256;
    proj_body<768>(Ain, waT, ba, aOut, b * 64, &As[0][0], (b % 12) * 64);
  }
}

// ---------- MLP GEMM: r0 config restored EXACTLY (proven best: 128x128,
// grid (8,128), 256 thr, 3 blocks/CU). r5/r6 fatter tiles both regressed. ----
__global__ __launch_bounds__(256, 3) void gemm_gelu_w2(const u16* __restrict__ Axb,
                                                       const u16* __restrict__ Bt,
                                                       const float* __restrict__ b1,
                                                       const float* __restrict__ W2,
                                                       float* __restrict__ logits) {
  constexpr int K = 768;
  __shared__ u16 As[128 * 64];   // 16 KB
  __shared__ u16 Bs[128 * 64];   // 16 KB
  const int tid = threadIdx.x;
  const int n0 = blockIdx.x * 128;   // x = n: consecutive blocks share A m-tile
  const int m0 = blockIdx.y * 128;
  const int wave = tid >> 6, lane = tid & 63, qm = lane & 15, quad = lane >> 4;
  const int rw = (wave >> 1) * 64, cw = (wave & 1) * 64;

  const int crow = tid >> 3;
  const int cpart = (tid & 7) ^ (crow & 7);
  const u16* Ap[4];
  const u16* Bp[4];
#pragma unroll
  for (int g = 0; g < 4; g++) {
    Ap[g] = Axb + (size_t)(m0 + crow + g * 32) * K + cpart * 8;
    Bp[g] = Bt + (size_t)(n0 + crow + g * 32) * K + cpart * 8;
  }

  f32x4 acc[4][4] = {};
  for (int kt = 0; kt < K; kt += 64) {
#pragma unroll
    for (int g = 0; g < 4; g++) gl_lds16(Ap[g] + kt, &As[(tid + g * 256) * 8]);
#pragma unroll
    for (int g = 0; g < 4; g++) gl_lds16(Bp[g] + kt, &Bs[(tid + g * 256) * 8]);
    __syncthreads();
#pragma unroll
    for (int s = 0; s < 2; s++) {
      short8 af[4], bfr[4];
#pragma unroll
      for (int i = 0; i < 4; i++) {
        const int r = rw + i * 16 + qm;
        af[i] = *(const short8*)&As[r * 64 + ((s * 4 + quad) ^ (r & 7)) * 8];
      }
#pragma unroll
      for (int j = 0; j < 4; j++) {
        const int r = cw + j * 16 + qm;
        bfr[j] = *(const short8*)&Bs[r * 64 + ((s * 4 + quad) ^ (r & 7)) * 8];
      }
#pragma unroll
      for (int i = 0; i < 4; i++)
#pragma unroll
        for (int j = 0; j < 4; j++)
          acc[i][j] = __builtin_amdgcn_mfma_f32_16x16x32_bf16(af[i], bfr[j], acc[i][j], 0, 0, 0);
    }
    __syncthreads();
  }

  // epilogue: partial logit = sum_j gelu(acc+b1)*W2; reduce over qm lanes; 1 atomic/row
  float w2j[4], bc[4];
#pragma unroll
  for (int j = 0; j < 4; j++) {
    const int col = n0 + cw + j * 16 + qm;
    w2j[j] = W2[col];
    bc[j] = b1[col];
  }
#pragma unroll
  for (int i = 0; i < 4; i++) {
#pragma unroll
    for (int r = 0; r < 4; r++) {
      float p = 0.0f;
#pragma unroll
      for (int j = 0; j < 4; j++)
        p += gelu_f(acc[i][j][r] + bc[j]) * w2j[j];
      p += __shfl_xor(p, 1);
      p += __shfl_xor(p, 2);
      p += __shfl_xor(p, 4);
      p += __shfl_xor(p, 8);
      if (qm == 0)
        atomicAdd(&logits[m0 + rw + i * 16 + quad * 4 + r], p);
    }
  }
}

// ---------- fused: fractional shift + window avg + l2norm(actx,v) + concat ----------
// v2: SLIDING CONVOLUTION. Since delta in [2,6] > 0, center == t always, so
// M.a_shift is a uniform trailing-window conv: out[t] = (1/6) sum_{m=t-5-ni}
// ^{t-ni} g[m], g[m] = a[m] + alpha*(a[m+1]-a[m]). One wave handles 8
// consecutive rows sharing a sliding register over 14 source rows ->
// 14 loads/8 rows = 1.75/row instead of 12 (-85% of a-row requests).
// Interior rows: identical op order as naive (tau ascending). t<16: original
// clipped path, bit-identical.
__global__ __launch_bounds__(256) void shift_norm(const float* __restrict__ a,
                                                  const float* __restrict__ v,
                                                  float* __restrict__ actx,
                                                  u16* __restrict__ xb,
                                                  const float* __restrict__ theta) {
  const int wave = threadIdx.x >> 6, lane = threadIdx.x & 63;
  const int wrow = blockIdx.x * 32 + wave * 8;   // first of this wave's 8 rows
  const int d4 = lane * 4;
  const int bb = wrow >> 11;
  const int tb = wrow & (T_SEQ - 1);             // 8-aligned, never crosses batch
  const float th = fminf(fmaxf(theta[0], -12.0f), 12.0f);
  const float delta = 2.0f + 4.0f * (1.0f / (1.0f + expf(-th)));
  const float dl = fminf(fmaxf(delta, 0.0f), (float)(T_SEQ - 1));
  const float nf = floorf(dl);
  const float alpha = dl - nf;
  const int ni = (int)nf;                        // 2..6
  const float* ab = a + (size_t)bb * T_SEQ * 256;

  float4 o[8];
  if (tb >= 16) {
    // ---- fast path: s0 = tb-ni-5 >= 5; sources s0..s0+13, g[0..12] ----
    const int s0 = tb - ni - 5;
    const float* arow0 = ab + (size_t)s0 * 256 + d4;
    float4 sum[8];
#pragma unroll
    for (int r = 0; r < 8; r++) { sum[r].x = 0; sum[r].y = 0; sum[r].z = 0; sum[r].w = 0; }
    float4 prev = *(const float4*)(arow0);
#pragma unroll
    for (int m = 0; m < 13; m++) {
      const float4 cur = *(const float4*)(arow0 + (size_t)(m + 1) * 256);
      float4 g;
      g.x = prev.x + alpha * (cur.x - prev.x);
      g.y = prev.y + alpha * (cur.y - prev.y);
      g.z = prev.z + alpha * (cur.z - prev.z);
      g.w = prev.w + alpha * (cur.w - prev.w);
#pragma unroll
      for (int r = 0; r < 8; r++)
        if (r <= m && m <= r + 5) {   // compile-time predicate after unroll
          sum[r].x += g.x; sum[r].y += g.y; sum[r].z += g.z; sum[r].w += g.w;
        }
      prev = cur;
    }
    const float sc = 1.0f / 6.0f;
#pragma unroll
    for (int r = 0; r < 8; r++) {
      o[r].x = sum[r].x * sc; o[r].y = sum[r].y * sc;
      o[r].z = sum[r].z * sc; o[r].w = sum[r].w * sc;
    }
  } else {
    // ---- slow path (tb in {0,8}): original clipped per-tau loop ----
#pragma unroll
    for (int r = 0; r < 8; r++) {
      const int t = tb + r;
      const float center = fminf(fmaxf((float)t + delta, 0.0f), (float)t);
      float sx = 0, sy = 0, sz = 0, sw = 0, cnt = 0.0f;
#pragma unroll
      for (int j = 0; j < 6; j++) {
        const int tau = t - 5 + j;
        if (tau < 0) continue;
        if (fabsf((float)tau - center) > 5.0f) continue;
        cnt += 1.0f;
        const int i0 = min(max(tau - ni, 0), T_SEQ - 1);
        const int i1 = min(i0 + 1, T_SEQ - 1);
        const float4 a0 = *(const float4*)&ab[(size_t)i0 * 256 + d4];
        const float4 a1 = *(const float4*)&ab[(size_t)i1 * 256 + d4];
        sx += a0.x + alpha * (a1.x - a0.x);
        sy += a0.y + alpha * (a1.y - a0.y);
        sz += a0.z + alpha * (a1.z - a0.z);
        sw += a0.w + alpha * (a1.w - a0.w);
      }
      const float sc = 1.0f / fmaxf(cnt, 1e-8f);
      o[r].x = sx * sc; o[r].y = sy * sc; o[r].z = sz * sc; o[r].w = sw * sc;
    }
  }

  // ---- shared epilogue: actx write, l2norms, xb concat ----
#pragma unroll
  for (int r = 0; r < 8; r++) {
    const int row = wrow + r;
    *(float4*)&actx[(size_t)row * 256 + d4] = o[r];
    const float4 vv = *(const float4*)&v[(size_t)row * 256 + d4];
    float sa2 = o[r].x * o[r].x + o[r].y * o[r].y + o[r].z * o[r].z + o[r].w * o[r].w;
    float sv2 = vv.x * vv.x + vv.y * vv.y + vv.z * vv.z + vv.w * vv.w;
    sa2 = wave_bcast_sum(sa2);
    sv2 = wave_bcast_sum(sv2);
    const float ia = 1.0f / fmaxf(sqrtf(sa2), 1e-8f);
    const float iv = 1.0f / fmaxf(sqrtf(sv2), 1e-8f);
    const float anx = o[r].x * ia, any_ = o[r].y * ia, anz = o[r].z * ia, anw = o[r].w * ia;
    const float vnx = vv.x * iv, vny = vv.y * iv, vnz = vv.z * iv, vnw = vv.w * iv;
    u16* xr = xb + (size_t)row * 768;
    u32 pa[2] = {pkbf(anx, any_), pkbf(anz, anw)};
    u32 pv[2] = {pkbf(vnx, vny), pkbf(vnz, vnw)};
    u32 pp[2] = {pkbf(anx * vnx, any_ * vny), pkbf(anz * vnz, anw * vnw)};
    *(uint2*)&xr[d4] = *(uint2*)pa;
    *(uint2*)&xr[256 + d4] = *(uint2*)pv;
    *(uint2*)&xr[512 + d4] = *(uint2*)pp;
  }
}

// ---------- gate + mix ----------
__global__ __launch_bounds__(256) void gate_mix(const float* __restrict__ logits,
                                                const float* __restrict__ b2,
                                                const float* __restrict__ actx,
                                                const float* __restrict__ v,
                                                float* __restrict__ out) {
  const int row = blockIdx.x * 4 + (threadIdx.x >> 6);
  const int lane = threadIdx.x & 63;
  const float l = fminf(fmaxf(logits[row] + b2[0], -12.0f), 12.0f);
  float g = 1.0f / (1.0f + expf(-l));
  g = fminf(fmaxf(g, 0.05f), 0.95f);
  const float4 aa = *(const float4*)&actx[(size_t)row * 256 + lane * 4];
  const float4 vv = *(const float4*)&v[(size_t)row * 256 + lane * 4];
  float4 o;
  o.x = g * aa.x + (1.0f - g) * vv.x;
  o.y = g * aa.y + (1.0f - g) * vv.y;
  o.z = g * aa.z + (1.0f - g) * vv.z;
  o.w = g * aa.w + (1.0f - g) * vv.w;
  *(float4*)&out[(size_t)row * 256 + lane * 4] = o;
}

// ---------- launch ----------
extern "C" void kernel_launch(void* const* d_in, const int* in_sizes, int n_in,
                              void* d_out, int out_size, void* d_ws, size_t ws_size,
                              hipStream_t stream) {
  const float* video = (const float*)d_in[0];
  const float* audio = (const float*)d_in[1];
  const float* Wv    = (const float*)d_in[2];
  const float* bv    = (const float*)d_in[3];
  const float* Wa    = (const float*)d_in[4];
  const float* ba    = (const float*)d_in[5];
  const float* theta = (const float*)d_in[6];
  const float* W1    = (const float*)d_in[7];
  const float* b1    = (const float*)d_in[8];
  const float* W2    = (const float*)d_in[9];
  const float* b2    = (const float*)d_in[10];
  float* out = (float*)d_out;
  char* ws = (char*)d_ws;

  const size_t OFF_WVT = 0;          // [256][1024] bf16 = 512 KB
  const size_t OFF_WAT = 524288;     // [256][768]  bf16 = 384 KB
  const size_t OFF_W1T = 917504;     // [1024][768] bf16 = 1.5 MB
  const size_t OFF_LOG = 2490368;    // [16384] f32 = 64 KB
  const size_t OFF_V   = 2555904;    // [16384][256] f32 = 16 MB (LN'd v)
  const size_t OFF_A   = 19333120;   // [16384][256] f32 = 16 MB (LN'd a)
  const size_t OFF_ACTX= 36110336;   // [16384][256] f32 = 16 MB
  const size_t OFF_XB  = 52887552;   // [16384][768] bf16 = 24 MB

  u16* wvT = (u16*)(ws + OFF_WVT);
  u16* waT = (u16*)(ws + OFF_WAT);
  u16* w1T = (u16*)(ws + OFF_W1T);
  float* logits = (float*)(ws + OFF_LOG);
  float* v    = (float*)(ws + OFF_V);
  float* a    = (float*)(ws + OFF_A);
  float* actx = (float*)(ws + OFF_ACTX);
  u16* xb = (u16*)(ws + OFF_XB);

  tcvt_all<<<1280, 256, 0, stream>>>(Wv, Wa, W1, wvT, waT, w1T, logits);
  proj_ln<<<512, 256, 0, stream>>>(video, audio, wvT, waT, bv, ba, v, a);
  shift_norm<<<BT_ROWS / 32, 256, 0, stream>>>(a, v, actx, xb, theta);
  gemm_gelu_w2<<<dim3(8, BT_ROWS / 128), 256, 0, stream>>>(xb, w1T, b1, W2, logits);
  gate_mix<<<BT_ROWS / 4, 256, 0, stream>>>(logits, b2, actx, v, out);
}

// Round 8
// 235.455 us; speedup vs baseline: 1.0747x; 1.0582x over previous
//
#include <hip/hip_runtime.h>
#include <cstdint>
#include <cstddef>

typedef unsigned short u16;
typedef unsigned int u32;
typedef __attribute__((ext_vector_type(8))) short short8;
typedef __attribute__((ext_vector_type(4))) float f32x4;

#define T_SEQ 2048
#define BT_ROWS 16384

// ---------- helpers ----------
__device__ __forceinline__ u16 f2bf(float x) {
  union { float f; u32 u; } v; v.f = x;
  u32 r = v.u + 0x7fffu + ((v.u >> 16) & 1u);
  return (u16)(r >> 16);
}
// pack two floats -> two bf16 in one u32 (lo in low half)
__device__ __forceinline__ u32 pkbf(float lo, float hi) {
  union { float f; u32 u; } a, b; a.f = lo; b.f = hi;
  const u32 ra = a.u + 0x7fffu + ((a.u >> 16) & 1u);
  const u32 rb = b.u + 0x7fffu + ((b.u >> 16) & 1u);
  return __builtin_amdgcn_perm(rb, ra, 0x07060302);
}
__device__ __forceinline__ float wave_bcast_sum(float x) {
#pragma unroll
  for (int off = 32; off > 0; off >>= 1) x += __shfl_down(x, off);
  return __shfl(x, 0);
}
__device__ __forceinline__ void gl_lds16(const void* g, void* l) {
  __builtin_amdgcn_global_load_lds((const __attribute__((address_space(1))) u32*)g,
                                   (__attribute__((address_space(3))) u32*)l, 16, 0, 0);
}
// tanh-form GELU; |diff| vs erf ~3e-4
__device__ __forceinline__ float gelu_f(float x) {
  float z = 1.5957691216057308f * x * (1.0f + 0.044715f * x * x);
  float e = __expf(z);
  return x - x * __builtin_amdgcn_rcpf(1.0f + e);
}
// release-barrier: publish LDS writes, do NOT drain vmcnt (keep global loads flying)
__device__ __forceinline__ void lgkm_barrier() {
  asm volatile("s_waitcnt lgkmcnt(0)" ::: "memory");
  __builtin_amdgcn_s_barrier();
}

// ---------- transpose+convert all 3 weights + zero logits ----------
__global__ __launch_bounds__(256) void tcvt_all(const float* __restrict__ Wv,
                                                const float* __restrict__ Wa,
                                                const float* __restrict__ W1,
                                                u16* __restrict__ wvT,
                                                u16* __restrict__ waT,
                                                u16* __restrict__ w1T,
                                                float* __restrict__ logits) {
  int b = blockIdx.x;
  if (b >= 1216) {  // 64 blocks zero the 16384-float logits buffer
    logits[(b - 1216) * 256 + threadIdx.x] = 0.0f;
    return;
  }
  __shared__ float tile[32][33];
  const float* in; u16* out; int K, N, bx, by;
  if (b < 256)      { in = Wv; out = wvT; K = 1024; N = 256;  bx = b & 31;  by = b >> 5; }
  else if (b < 448) { b -= 256; in = Wa; out = waT; K = 768; N = 256;  bx = b % 24; by = b / 24; }
  else              { b -= 448; in = W1; out = w1T; K = 768; N = 1024; bx = b % 24; by = b / 24; }
  const int k0 = bx * 32, n0 = by * 32;
  const int tx = threadIdx.x & 31, ty = threadIdx.x >> 5;
#pragma unroll
  for (int r = 0; r < 4; r++)
    tile[ty + r * 8][tx] = in[(size_t)(k0 + ty + r * 8) * N + n0 + tx];
  __syncthreads();
#pragma unroll
  for (int r = 0; r < 4; r++)
    out[(size_t)(n0 + ty + r * 8) * K + k0 + tx] = f2bf(tile[tx][ty + r * 8]);
}

// ---------- projection GEMM with FUSED LayerNorm, tile 64x256 (r3 config) ----------
// Mt=64, 256 thr, grid 512 (2 blocks/CU) — empirically the best config (58 µs,
// stable across 3 runs, at the per-CU vmem request cap). K-phase rotation +
// B-in-registers + lgkm-only barrier. DO NOT retile (r4/r5 both regressed).
template <int K>
__device__ __forceinline__ void proj_body(const float* __restrict__ A,
                                          const u16* __restrict__ Bt,
                                          const float* __restrict__ bias,
                                          float* __restrict__ C,
                                          int m0, u16* As, int k0) {
  constexpr int NT = K / 64;
  const int tid = threadIdx.x;
  const int wave = tid >> 6, lane = tid & 63, qm = lane & 15, quad = lane >> 4;
  const int cw = wave * 64;   // wave owns a 64-col quarter, all 64 rows

  // A register staging: thread owns row ar = tid>>2, 16 consecutive floats.
  const int ar = tid >> 2;
  const float* Arow = A + (size_t)(m0 + ar) * K + (tid & 3) * 4;
  int awAddr[4];
#pragma unroll
  for (int g = 0; g < 4; g++) {
    const int cg = ((tid & 3) >> 1) + 2 * g;
    awAddr[g] = ar * 64 + ((cg ^ (ar & 7)) * 8) + (tid & 1) * 4;
  }
  // B fragment row pointers (row = output col); chunk offset = quad*8 + s*32
  const u16* brow[4];
#pragma unroll
  for (int j = 0; j < 4; j++)
    brow[j] = Bt + (size_t)(cw + j * 16 + qm) * K + quad * 8;

  f32x4 acc[4][4] = {};
  short8 bfrag[2][8];
  float4 p[4];

  int koff = k0;   // current K-tile element offset (circular)

  // ---- prologue: A(koff) -> As[0], B(koff) -> bfrag[0] ----
#pragma unroll
  for (int g = 0; g < 4; g++) p[g] = *(const float4*)(Arow + koff + g * 16);
#pragma unroll
  for (int s = 0; s < 2; s++)
#pragma unroll
    for (int j = 0; j < 4; j++)
      bfrag[0][s * 4 + j] = *(const short8*)(brow[j] + koff + s * 32);
#pragma unroll
  for (int g = 0; g < 4; g++) {
    uint2 w; w.x = pkbf(p[g].x, p[g].y); w.y = pkbf(p[g].z, p[g].w);
    *(uint2*)&As[awAddr[g]] = w;
  }
  lgkm_barrier();

#pragma unroll
  for (int t = 0; t < NT; t++) {
    const int cb = t & 1, nb = cb ^ 1;
    int knext = koff + 64;
    if (knext == K) knext = 0;   // circular K walk
    if (t + 1 < NT) {  // issue next-tile loads; they fly across the barrier
#pragma unroll
      for (int g = 0; g < 4; g++)
        p[g] = *(const float4*)(Arow + knext + g * 16);
#pragma unroll
      for (int s = 0; s < 2; s++)
#pragma unroll
        for (int j = 0; j < 4; j++)
          bfrag[nb][s * 4 + j] = *(const short8*)(brow[j] + knext + s * 32);
    }
#pragma unroll
    for (int s = 0; s < 2; s++) {
      short8 af[4];
#pragma unroll
      for (int i = 0; i < 4; i++) {
        const int r = i * 16 + qm;
        af[i] = *(const short8*)&As[cb * 4096 + r * 64 + ((s * 4 + quad) ^ (r & 7)) * 8];
      }
      __builtin_amdgcn_s_setprio(1);
#pragma unroll
      for (int i = 0; i < 4; i++)
#pragma unroll
        for (int j = 0; j < 4; j++)
          acc[i][j] = __builtin_amdgcn_mfma_f32_16x16x32_bf16(
              af[i], bfrag[cb][s * 4 + j], acc[i][j], 0, 0, 0);
      __builtin_amdgcn_s_setprio(0);
    }
    if (t + 1 < NT) {  // convert+publish next A tile (p landed under MFMAs)
#pragma unroll
      for (int g = 0; g < 4; g++) {
        uint2 w; w.x = pkbf(p[g].x, p[g].y); w.y = pkbf(p[g].z, p[g].w);
        *(uint2*)&As[nb * 4096 + awAddr[g]] = w;
      }
      lgkm_barrier();
    }
    koff = knext;
  }

  // ---- fused bias + LayerNorm epilogue over 64 rows ----
  float bcol[4];
#pragma unroll
  for (int j = 0; j < 4; j++) bcol[j] = bias[cw + j * 16 + qm];
#pragma unroll
  for (int i = 0; i < 4; i++)
#pragma unroll
    for (int j = 0; j < 4; j++)
#pragma unroll
      for (int r = 0; r < 4; r++)
        acc[i][j][r] += bcol[j];
  float s1[4][4], s2[4][4];
#pragma unroll
  for (int i = 0; i < 4; i++)
#pragma unroll
    for (int r = 0; r < 4; r++) {
      float a1 = 0, a2 = 0;
#pragma unroll
      for (int j = 0; j < 4; j++) { a1 += acc[i][j][r]; a2 += acc[i][j][r] * acc[i][j][r]; }
#pragma unroll
      for (int off = 1; off < 16; off <<= 1) {
        a1 += __shfl_xor(a1, off);
        a2 += __shfl_xor(a2, off);
      }
      s1[i][r] = a1; s2[i][r] = a2;
    }
  __syncthreads();          // all waves done with K-loop LDS before scratch reuse
  float* red = (float*)As;
  if (qm == 0) {
#pragma unroll
    for (int i = 0; i < 4; i++)
#pragma unroll
      for (int r = 0; r < 4; r++) {
        const int row = i * 16 + quad * 4 + r;
        red[row * 8 + wave * 2] = s1[i][r];
        red[row * 8 + wave * 2 + 1] = s2[i][r];
      }
  }
  __syncthreads();
#pragma unroll
  for (int i = 0; i < 4; i++)
#pragma unroll
    for (int r = 0; r < 4; r++) {
      const int row = i * 16 + quad * 4 + r;   // D: row = quad*4 + reg (+ i*16)
      const float4 q1 = *(const float4*)&red[row * 8];
      const float4 q2 = *(const float4*)&red[row * 8 + 4];
      const float st = q1.x + q1.z + q2.x + q2.z;
      const float st2 = q1.y + q1.w + q2.y + q2.w;
      const float mu = st * (1.0f / 256.0f);
      const float var = st2 * (1.0f / 256.0f) - mu * mu;
      const float inv = rsqrtf(var + 1e-5f);
#pragma unroll
      for (int j = 0; j < 4; j++)
        C[(size_t)(m0 + row) * 256 + cw + j * 16 + qm] = (acc[i][j][r] - mu) * inv;
    }
}

__global__ __launch_bounds__(256, 2) void proj_ln(const float* __restrict__ Vin,
                                                  const float* __restrict__ Ain,
                                                  const u16* __restrict__ wvT,
                                                  const u16* __restrict__ waT,
                                                  const float* __restrict__ bv,
                                                  const float* __restrict__ ba,
                                                  float* __restrict__ vOut,
                                                  float* __restrict__ aOut) {
  __shared__ __align__(16) u16 As[2][64 * 64];   // 16 KB total (A dbuf, bf16)
  int b = blockIdx.x;
  if (b < 256)
    proj_body<1024>(Vin, wvT, bv, vOut, b * 64, &As[0][0], (b & 15) * 64);
  else {
    b -= 256;
    proj_body<768>(Ain, waT, ba, aOut, b * 64, &As[0][0], (b % 12) * 64);
  }
}

// ---------- MLP GEMM: 256x256 tile (byte-minimal, 192 MB), grid (4,64)=256
// = 1 block/CU, now DOUBLE-BUFFERED so the single resident block hides the
// vmcnt drain under its own MFMA phase (r5 showed 1/CU + single-buffer
// collapses the rate; r0 hid the drain with 3 co-resident blocks).
// LDS 128 KB (fits 160 KB/CU at 1 block). One barrier per K-step, drain
// placed AFTER compute. ----
__global__ __launch_bounds__(512, 2) void gemm_gelu_w2(const u16* __restrict__ Axb,
                                                       const u16* __restrict__ Bt,
                                                       const float* __restrict__ b1,
                                                       const float* __restrict__ W2,
                                                       float* __restrict__ logits) {
  constexpr int K = 768;
  constexpr int NT = K / 64;     // 12
  __shared__ u16 As[2][256 * 64];   // 64 KB
  __shared__ u16 Bs[2][256 * 64];   // 64 KB
  const int tid = threadIdx.x;       // 0..511
  const int n0 = blockIdx.x * 256;   // x = n: consecutive blocks share A m-tile
  const int m0 = blockIdx.y * 256;
  const int wave = tid >> 6, lane = tid & 63, qm = lane & 15, quad = lane >> 4;
  const int rw = (wave >> 1) * 64, cw = (wave & 1) * 128;

  // staging: instr g covers LDS rows (tid>>3)+g*64 linearly; in-row chunk
  // (tid&7); source pre-swizzled by xor-8 so swizzled reads land correctly.
  const u16* Ap[4];
  const u16* Bp[4];
#pragma unroll
  for (int g = 0; g < 4; g++) {
    const int r = (tid >> 3) + g * 64;
    const int cc = (tid & 7) ^ (r & 7);
    Ap[g] = Axb + (size_t)(m0 + r) * K + cc * 8;
    Bp[g] = Bt + (size_t)(n0 + r) * K + cc * 8;
  }

  f32x4 acc[4][8] = {};

  // ---- prologue: stage tile 0 into buffer 0, drain, barrier ----
#pragma unroll
  for (int g = 0; g < 4; g++) gl_lds16(Ap[g], &As[0][(tid + g * 512) * 8]);
#pragma unroll
  for (int g = 0; g < 4; g++) gl_lds16(Bp[g], &Bs[0][(tid + g * 512) * 8]);
  asm volatile("s_waitcnt vmcnt(0)" ::: "memory");
  __builtin_amdgcn_s_barrier();

#pragma unroll
  for (int t = 0; t < NT; t++) {
    const int cb = t & 1, nb = cb ^ 1;
    const int ktn = (t + 1) * 64;
    if (t + 1 < NT) {   // issue next-tile loads FIRST; compute hides latency
#pragma unroll
      for (int g = 0; g < 4; g++) gl_lds16(Ap[g] + ktn, &As[nb][(tid + g * 512) * 8]);
#pragma unroll
      for (int g = 0; g < 4; g++) gl_lds16(Bp[g] + ktn, &Bs[nb][(tid + g * 512) * 8]);
    }
#pragma unroll
    for (int s = 0; s < 2; s++) {
      short8 af[4], bfr[8];
#pragma unroll
      for (int i = 0; i < 4; i++) {
        const int r = rw + i * 16 + qm;
        af[i] = *(const short8*)&As[cb][r * 64 + ((s * 4 + quad) ^ (r & 7)) * 8];
      }
#pragma unroll
      for (int j = 0; j < 8; j++) {
        const int r = cw + j * 16 + qm;
        bfr[j] = *(const short8*)&Bs[cb][r * 64 + ((s * 4 + quad) ^ (r & 7)) * 8];
      }
      __builtin_amdgcn_s_setprio(1);
#pragma unroll
      for (int i = 0; i < 4; i++)
#pragma unroll
        for (int j = 0; j < 8; j++)
          acc[i][j] = __builtin_amdgcn_mfma_f32_16x16x32_bf16(af[i], bfr[j], acc[i][j], 0, 0, 0);
      __builtin_amdgcn_s_setprio(0);
    }
    if (t + 1 < NT)   // drain AFTER compute: nb fully written, latency hidden
      asm volatile("s_waitcnt vmcnt(0)" ::: "memory");
    __builtin_amdgcn_s_barrier();   // all waves done reading cb; nb published
  }

  // epilogue: partial logit = sum_j gelu(acc+b1)*W2; reduce over qm lanes; 1 atomic/row
  float w2j[8], bc[8];
#pragma unroll
  for (int j = 0; j < 8; j++) {
    const int col = n0 + cw + j * 16 + qm;
    w2j[j] = W2[col];
    bc[j] = b1[col];
  }
#pragma unroll
  for (int i = 0; i < 4; i++) {
#pragma unroll
    for (int r = 0; r < 4; r++) {
      float p = 0.0f;
#pragma unroll
      for (int j = 0; j < 8; j++)
        p += gelu_f(acc[i][j][r] + bc[j]) * w2j[j];
      p += __shfl_xor(p, 1);
      p += __shfl_xor(p, 2);
      p += __shfl_xor(p, 4);
      p += __shfl_xor(p, 8);
      if (qm == 0)
        atomicAdd(&logits[m0 + rw + i * 16 + quad * 4 + r], p);
    }
  }
}

// ---------- fused: fractional shift + window avg + l2norm(actx,v) + concat ----------
// Reverted to the r0-r3 naive form: grid 4096, 1 row/wave. The r7 sliding-conv
// variant regressed ~9 µs (register pressure + serialized reductions + low
// TLP beat the request savings — caches were already absorbing the overlap).
__global__ __launch_bounds__(256) void shift_norm(const float* __restrict__ a,
                                                  const float* __restrict__ v,
                                                  float* __restrict__ actx,
                                                  u16* __restrict__ xb,
                                                  const float* __restrict__ theta) {
  const int row = blockIdx.x * 4 + (threadIdx.x >> 6);
  const int lane = threadIdx.x & 63;
  const int d4 = lane * 4;
  const int bb = row >> 11;
  const int t = row & (T_SEQ - 1);
  const float th = fminf(fmaxf(theta[0], -12.0f), 12.0f);
  const float delta = 2.0f + 4.0f * (1.0f / (1.0f + expf(-th)));
  const float dl = fminf(fmaxf(delta, 0.0f), (float)(T_SEQ - 1));
  const float nf = floorf(dl);
  const float alpha = dl - nf;
  const int ni = (int)nf;
  const float center = fminf(fmaxf((float)t + delta, 0.0f), (float)t);
  float sx = 0, sy = 0, sz = 0, sw = 0, cnt = 0.0f;
  const float* ab = a + (size_t)bb * T_SEQ * 256;
#pragma unroll
  for (int j = 0; j < 6; j++) {
    const int tau = t - 5 + j;
    if (tau < 0) continue;
    if (fabsf((float)tau - center) > 5.0f) continue;
    cnt += 1.0f;
    const int i0 = min(max(tau - ni, 0), T_SEQ - 1);
    const int i1 = min(i0 + 1, T_SEQ - 1);
    const float4 a0 = *(const float4*)&ab[(size_t)i0 * 256 + d4];
    const float4 a1 = *(const float4*)&ab[(size_t)i1 * 256 + d4];
    sx += a0.x + alpha * (a1.x - a0.x);
    sy += a0.y + alpha * (a1.y - a0.y);
    sz += a0.z + alpha * (a1.z - a0.z);
    sw += a0.w + alpha * (a1.w - a0.w);
  }
  const float sc = 1.0f / fmaxf(cnt, 1e-8f);
  float4 o; o.x = sx * sc; o.y = sy * sc; o.z = sz * sc; o.w = sw * sc;
  *(float4*)&actx[(size_t)row * 256 + d4] = o;
  const float4 vv = *(const float4*)&v[(size_t)row * 256 + d4];
  float sa2 = o.x * o.x + o.y * o.y + o.z * o.z + o.w * o.w;
  float sv2 = vv.x * vv.x + vv.y * vv.y + vv.z * vv.z + vv.w * vv.w;
  sa2 = wave_bcast_sum(sa2);
  sv2 = wave_bcast_sum(sv2);
  const float ia = 1.0f / fmaxf(sqrtf(sa2), 1e-8f);
  const float iv = 1.0f / fmaxf(sqrtf(sv2), 1e-8f);
  const float anx = o.x * ia, any_ = o.y * ia, anz = o.z * ia, anw = o.w * ia;
  const float vnx = vv.x * iv, vny = vv.y * iv, vnz = vv.z * iv, vnw = vv.w * iv;
  u16* xr = xb + (size_t)row * 768;
  u32 pa[2] = {pkbf(anx, any_), pkbf(anz, anw)};
  u32 pv[2] = {pkbf(vnx, vny), pkbf(vnz, vnw)};
  u32 pp[2] = {pkbf(anx * vnx, any_ * vny), pkbf(anz * vnz, anw * vnw)};
  *(uint2*)&xr[d4] = *(uint2*)pa;
  *(uint2*)&xr[256 + d4] = *(uint2*)pv;
  *(uint2*)&xr[512 + d4] = *(uint2*)pp;
}

// ---------- gate + mix ----------
__global__ __launch_bounds__(256) void gate_mix(const float* __restrict__ logits,
                                                const float* __restrict__ b2,
                                                const float* __restrict__ actx,
                                                const float* __restrict__ v,
                                                float* __restrict__ out) {
  const int row = blockIdx.x * 4 + (threadIdx.x >> 6);
  const int lane = threadIdx.x & 63;
  const float l = fminf(fmaxf(logits[row] + b2[0], -12.0f), 12.0f);
  float g = 1.0f / (1.0f + expf(-l));
  g = fminf(fmaxf(g, 0.05f), 0.95f);
  const float4 aa = *(const float4*)&actx[(size_t)row * 256 + lane * 4];
  const float4 vv = *(const float4*)&v[(size_t)row * 256 + lane * 4];
  float4 o;
  o.x = g * aa.x + (1.0f - g) * vv.x;
  o.y = g * aa.y + (1.0f - g) * vv.y;
  o.z = g * aa.z + (1.0f - g) * vv.z;
  o.w = g * aa.w + (1.0f - g) * vv.w;
  *(float4*)&out[(size_t)row * 256 + lane * 4] = o;
}

// ---------- launch ----------
extern "C" void kernel_launch(void* const* d_in, const int* in_sizes, int n_in,
                              void* d_out, int out_size, void* d_ws, size_t ws_size,
                              hipStream_t stream) {
  const float* video = (const float*)d_in[0];
  const float* audio = (const float*)d_in[1];
  const float* Wv    = (const float*)d_in[2];
  const float* bv    = (const float*)d_in[3];
  const float* Wa    = (const float*)d_in[4];
  const float* ba    = (const float*)d_in[5];
  const float* theta = (const float*)d_in[6];
  const float* W1    = (const float*)d_in[7];
  const float* b1    = (const float*)d_in[8];
  const float* W2    = (const float*)d_in[9];
  const float* b2    = (const float*)d_in[10];
  float* out = (float*)d_out;
  char* ws = (char*)d_ws;

  const size_t OFF_WVT = 0;          // [256][1024] bf16 = 512 KB
  const size_t OFF_WAT = 524288;     // [256][768]  bf16 = 384 KB
  const size_t OFF_W1T = 917504;     // [1024][768] bf16 = 1.5 MB
  const size_t OFF_LOG = 2490368;    // [16384] f32 = 64 KB
  const size_t OFF_V   = 2555904;    // [16384][256] f32 = 16 MB (LN'd v)
  const size_t OFF_A   = 19333120;   // [16384][256] f32 = 16 MB (LN'd a)
  const size_t OFF_ACTX= 36110336;   // [16384][256] f32 = 16 MB
  const size_t OFF_XB  = 52887552;   // [16384][768] bf16 = 24 MB

  u16* wvT = (u16*)(ws + OFF_WVT);
  u16* waT = (u16*)(ws + OFF_WAT);
  u16* w1T = (u16*)(ws + OFF_W1T);
  float* logits = (float*)(ws + OFF_LOG);
  float* v    = (float*)(ws + OFF_V);
  float* a    = (float*)(ws + OFF_A);
  float* actx = (float*)(ws + OFF_ACTX);
  u16* xb = (u16*)(ws + OFF_XB);

  tcvt_all<<<1280, 256, 0, stream>>>(Wv, Wa, W1, wvT, waT, w1T, logits);
  proj_ln<<<512, 256, 0, stream>>>(video, audio, wvT, waT, bv, ba, v, a);
  shift_norm<<<BT_ROWS / 4, 256, 0, stream>>>(a, v, actx, xb, theta);
  gemm_gelu_w2<<<dim3(4, 64), 512, 0, stream>>>(xb, w1T, b1, W2, logits);
  gate_mix<<<BT_ROWS / 4, 256, 0, stream>>>(logits, b2, actx, v, out);
}